// Round 1
// baseline (21730.309 us; speedup 1.0000x reference)
//
#include <hip/hip_runtime.h>

// QLSTMGen persistent-kernel version.
// Was: 1024 sequential mini-dispatches (14.3us each: launch overhead + per-step
// weight refetch + kernel-boundary drains). Now: ONE cooperative kernel runs all
// 512 steps; W1 pinned in 96 VGPR/wave of MFMA B-fragments, W2 slice in 48KB
// XOR-swizzled LDS, cx in LDS, x pre-converted to bf16 one step ahead (off the
// recurrence critical path), custom 2-level device-scope tree barrier (2/step).
//
// Folding (unchanged, proven): M1 = phase @ fe_W^T;
//   W2 = [M1 | M1@(Wr+Whr)^T,M1@(Wz+Whz)^T | M1@Win^T | M1@Whn^T]  (2560x512)
//   W1 = [Wih_x | Wih_h + Whh] (2048x768), biases folded.
// Phase A: gates=[x|hx]@W1^T -> LSTM -> h1 ; Phase B: h1@W2^T -> GRU -> hx,out.

#define T_ 512
#define B_ 256
#define D_ 256
#define H_ 512

typedef short v8s __attribute__((ext_vector_type(8)));
typedef float v4f __attribute__((ext_vector_type(4)));

__device__ __forceinline__ unsigned short f2bf(float f) {
  unsigned u = __float_as_uint(f);
  u = u + 0x7FFFu + ((u >> 16) & 1u);   // RNE
  return (unsigned short)(u >> 16);
}

__device__ __forceinline__ float sigf(float x) {
  return 1.0f / (1.0f + __expf(-x));
}

// ---------------- setup kernels (unchanged, proven) ----------------

__global__ __launch_bounds__(256) void k_setup_w1(
    const float* __restrict__ Wih, const float* __restrict__ Whh,
    const float* __restrict__ bih, const float* __restrict__ bhh,
    unsigned short* __restrict__ W1, float* __restrict__ b1)
{
  int idx = blockIdx.x * 256 + threadIdx.x;
  if (idx < 2048 * 768) {
    int n = idx / 768;
    int k = idx - n * 768;
    float v = Wih[idx];
    if (k >= 256) v += Whh[n * 512 + (k - 256)];
    W1[idx] = f2bf(v);
  }
  if (idx < 2048) b1[idx] = bih[idx] + bhh[idx];
}

__global__ __launch_bounds__(256) void k_m1(
    const float* __restrict__ phase, const float* __restrict__ feW,
    float* __restrict__ M1f)
{
  int idx = blockIdx.x * 256 + threadIdx.x;   // 262144
  int k = idx >> 9, n = idx & 511;
  const float* pr = phase + k * 512;
  const float* fr = feW + n * 512;
  float s = 0.f;
  #pragma unroll 8
  for (int j = 0; j < 512; ++j) s += pr[j] * fr[j];
  M1f[idx] = s;
}

__global__ __launch_bounds__(256) void k_setup_w2(
    const float* __restrict__ M1f, const float* __restrict__ gWih,
    const float* __restrict__ gWhh, unsigned short* __restrict__ W2)
{
  int idx = blockIdx.x * 256 + threadIdx.x;
  if (idx >= 2560 * 512) return;
  int np = idx >> 9;
  int k  = idx & 511;
  const float* m1k = M1f + k * 512;
  float s = 0.f;
  if (np < 512) {
    s = m1k[np];
  } else if (np < 1536) {
    int c = np - 512;
    const float* a = gWih + c * 512;
    const float* b = gWhh + c * 512;
    #pragma unroll 8
    for (int n = 0; n < 512; ++n) s += m1k[n] * (a[n] + b[n]);
  } else if (np < 2048) {
    int c = np - 1536 + 1024;
    const float* a = gWih + c * 512;
    #pragma unroll 8
    for (int n = 0; n < 512; ++n) s += m1k[n] * a[n];
  } else {
    int c = np - 2048 + 1024;
    const float* b = gWhh + c * 512;
    #pragma unroll 8
    for (int n = 0; n < 512; ++n) s += m1k[n] * b[n];
  }
  W2[idx] = f2bf(s);
}

__global__ __launch_bounds__(256) void k_setup_bias2(
    const float* __restrict__ feb, const float* __restrict__ gWih,
    const float* __restrict__ gWhh, const float* __restrict__ gbih,
    const float* __restrict__ gbhh, float* __restrict__ bias2)
{
  int np = blockIdx.x * 256 + threadIdx.x;
  if (np >= 2560) return;
  float s;
  if (np < 512) {
    s = feb[np];
  } else if (np < 1536) {
    int c = np - 512;
    s = gbih[c] + gbhh[c];
    for (int n = 0; n < 512; ++n) s += feb[n] * (gWih[c * 512 + n] + gWhh[c * 512 + n]);
  } else if (np < 2048) {
    int c = np - 1536 + 1024;
    s = gbih[c];
    for (int n = 0; n < 512; ++n) s += feb[n] * gWih[c * 512 + n];
  } else {
    int c = np - 2048 + 1024;
    s = gbhh[c];
    for (int n = 0; n < 512; ++n) s += feb[n] * gWhh[c * 512 + n];
  }
  bias2[np] = s;
}

// zero hx state and barrier counters
__global__ __launch_bounds__(256) void k_init(
    unsigned short* __restrict__ hx, unsigned* __restrict__ bar)
{
  int i = blockIdx.x * 256 + threadIdx.x;   // grid 256 -> i < 65536
  ((unsigned*)hx)[i] = 0u;
  if (i < 2048) bar[i] = 0u;
}

// ---------------- grid barrier ----------------
// 2-level tree: 32 group counters (8 same-XCD blocks each, 128B apart) -> root.
// Monotonic counters, round k (1-based): group-last bumps root; all spin on
// root >= k*32. Release RMW flushes XCD L2 (agent scope); acquire load
// invalidates before post-barrier reads (G16).

__device__ __forceinline__ void gridbar(unsigned* bar, int grpsel, unsigned k) {
  asm volatile("" ::: "memory");
  __syncthreads();
  if (threadIdx.x == 0) {
    unsigned old = __hip_atomic_fetch_add(bar + grpsel * 32, 1u,
                                          __ATOMIC_ACQ_REL, __HIP_MEMORY_SCOPE_AGENT);
    if (old == k * 8u - 1u)
      __hip_atomic_fetch_add(bar + 1024, 1u,
                             __ATOMIC_ACQ_REL, __HIP_MEMORY_SCOPE_AGENT);
    while (__hip_atomic_load(bar + 1024, __ATOMIC_RELAXED,
                             __HIP_MEMORY_SCOPE_AGENT) < k * 32u) {}
    (void)__hip_atomic_load(bar + 1024, __ATOMIC_ACQUIRE, __HIP_MEMORY_SCOPE_AGENT);
  }
  __syncthreads();
  asm volatile("" ::: "memory");
}

// ---------------- the persistent kernel ----------------
// 256 blocks x 256 threads (4 waves). Roles:
//  phase A: block = (mA = b>>5, jA = b&31): 32 m-rows x (4 gates x 16 j). W1
//           B-frags in registers (24 chunks x v8s = 96 VGPR/wave, wave = gate).
//  phase B: block = (mB = b>>6, jB = b&63): 64 m-rows x (5 groups x 8 j). W2
//           slice (40 rows x 512, padded to 48) in XOR-swizzled LDS; wave =
//           16-row m-tile, 3 n-tiles, K split in 2 -> 6 acc chains.

__global__ __launch_bounds__(256, 1) void k_persist(
    const float* __restrict__ x,           // [512][256][256] f32
    const unsigned short* __restrict__ W1, // [2048][768] bf16
    const float* __restrict__ b1,          // [2048]
    const unsigned short* __restrict__ W2, // [2560][512] bf16
    const float* __restrict__ bias2,       // [2560]
    unsigned short* __restrict__ hx,       // [256][512] bf16 state
    unsigned short* __restrict__ h1,       // [256][512] bf16 intermediate
    unsigned short* __restrict__ xb0,      // [256][256] bf16 x ping
    unsigned short* __restrict__ xb1,      // [256][256] bf16 x pong
    float* __restrict__ out,               // outputs | hx | cx
    unsigned* __restrict__ bar)
{
  __shared__ __align__(16) char w2s[49152]; // 48 rows x 1024B, swizzled
  __shared__ float ew[3136];                // union: A 4x32x17 | B 64x49
  __shared__ float cxs[512];                // cx [32m][16j], persists all steps
  __shared__ float b1s[64];
  __shared__ float b2s[48];

  const int tid  = threadIdx.x;
  const int b    = blockIdx.x;
  const int w    = tid >> 6;
  const int lane = tid & 63;
  const int l15  = lane & 15;
  const int quad = lane >> 4;
  const int m0A  = (b >> 5) << 5;
  const int j0A  = (b & 31) << 4;
  const int m0B  = (b >> 6) << 6;
  const int jbB  = b & 63;
  const int grpsel = b & 31;
  const unsigned swz = (unsigned)((l15 & 7) << 4);

  // ---- prologue: W2 slice -> swizzled LDS (rows 0..39; 40..47 zero pad) ----
  for (int u = tid; u < 2560; u += 256) {
    int r = u >> 6, c = u & 63;
    int g = r >> 3, jj = r & 7;
    const unsigned short* src = W2 + (size_t)(g * 512 + (jbB << 3) + jj) * 512 + (c << 3);
    *(v8s*)(w2s + r * 1024 + (((unsigned)(c << 4)) ^ ((unsigned)((r & 7) << 4)))) =
        *(const v8s*)src;
  }
  {
    v8s z = {0, 0, 0, 0, 0, 0, 0, 0};
    for (int u = tid; u < 512; u += 256) {
      int r = 40 + (u >> 6), c = u & 63;
      *(v8s*)(w2s + r * 1024 + (((unsigned)(c << 4)) ^ ((unsigned)((r & 7) << 4)))) = z;
    }
  }
  if (tid < 64) b1s[tid] = b1[((tid >> 4) << 9) + j0A + (tid & 15)];
  if (tid < 40) b2s[tid] = bias2[((tid >> 3) << 9) + (jbB << 3) + (tid & 7)];
  for (int u = tid; u < 512; u += 256) cxs[u] = 0.f;
  {
    int i = (b << 8) + tid;       // 0..65535: convert x_0 -> xb0
    xb0[i] = f2bf(x[i]);
  }
  // ---- W1 B-fragments pinned in registers (wave = gate) ----
  v8s bw1[24];
  {
    const unsigned short* Bp = W1 + (size_t)((w << 9) + j0A + l15) * 768 + (quad << 3);
    #pragma unroll
    for (int kc = 0; kc < 24; ++kc) bw1[kc] = *(const v8s*)(Bp + kc * 32);
  }
  const unsigned short* ap_h = hx + ((m0A + l15) << 9) + (quad << 3);
  const unsigned short* apB  = h1 + ((m0B + (w << 4) + l15) << 9) + (quad << 3);

  gridbar(bar, grpsel, 1u);

  for (int t = 0; t < T_; ++t) {
    // ================= phase A: [x|hx] @ W1^T -> LSTM -> h1, cx =================
    {
      const unsigned short* ap_x = ((t & 1) ? xb1 : xb0) + ((m0A + l15) << 8) + (quad << 3);
      v4f a00 = {0.f, 0.f, 0.f, 0.f};
      v4f a01 = a00, a10 = a00, a11 = a00;
      // chain h=0: kc=kk (x for kk<8, hx for 8..11); chain h=1: kc=12+kk (hx).
      // 4 independent acc chains (2 m-tiles x 2 K-halves) for MFMA latency.
      #pragma unroll
      for (int kk = 0; kk < 12; ++kk) {
        v8s f0, f1;
        if (kk < 8) {
          f0 = *(const v8s*)(ap_x + kk * 32);
          f1 = *(const v8s*)(ap_x + kk * 32 + 4096);   // +16 rows * 256
        } else {
          f0 = *(const v8s*)(ap_h + (kk - 8) * 32);
          f1 = *(const v8s*)(ap_h + (kk - 8) * 32 + 8192); // +16 rows * 512
        }
        v8s g0 = *(const v8s*)(ap_h + (kk + 4) * 32);
        v8s g1 = *(const v8s*)(ap_h + (kk + 4) * 32 + 8192);
        a00 = __builtin_amdgcn_mfma_f32_16x16x32_bf16(f0, bw1[kk],      a00, 0, 0, 0);
        a10 = __builtin_amdgcn_mfma_f32_16x16x32_bf16(f1, bw1[kk],      a10, 0, 0, 0);
        a01 = __builtin_amdgcn_mfma_f32_16x16x32_bf16(g0, bw1[12 + kk], a01, 0, 0, 0);
        a11 = __builtin_amdgcn_mfma_f32_16x16x32_bf16(g1, bw1[12 + kk], a11, 0, 0, 0);
      }
      v4f s0 = a00 + a01;
      v4f s1 = a10 + a11;
      {
        float* eb = ew + (w * 32 + (quad << 2)) * 17 + l15;  // [gate][32m][17]
        #pragma unroll
        for (int r = 0; r < 4; ++r) { eb[r * 17] = s0[r]; eb[(r + 16) * 17] = s1[r]; }
      }
      __syncthreads();
      {
        int p = tid << 1;
        int m = p >> 4, j = p & 15;        // j even
        const float* e = ew + m * 17 + j;  // gate stride = 32*17 = 544
        float ia = sigf(e[0]     + b1s[j]);
        float ib = sigf(e[1]     + b1s[j + 1]);
        float fa = sigf(e[544]   + b1s[16 + j]);
        float fb = sigf(e[545]   + b1s[17 + j]);
        float ga = tanhf(e[1088] + b1s[32 + j]);
        float gb = tanhf(e[1089] + b1s[33 + j]);
        float oa = sigf(e[1632]  + b1s[48 + j]);
        float ob = sigf(e[1633]  + b1s[49 + j]);
        float ca = fa * cxs[p]     + ia * ga;
        float cb = fb * cxs[p + 1] + ib * gb;
        cxs[p] = ca; cxs[p + 1] = cb;
        unsigned hv = (unsigned)f2bf(oa * tanhf(ca)) |
                      ((unsigned)f2bf(ob * tanhf(cb)) << 16);
        *(unsigned*)(h1 + ((size_t)(m0A + m) << 9) + j0A + j) = hv;
      }
    }
    gridbar(bar, grpsel, (unsigned)(2 * t + 2));
    // ================= phase B: h1 @ W2^T -> GRU -> hx, out =================
    {
      if (t < T_ - 1) {   // pre-convert x_{t+1} (off the critical path)
        unsigned short* xbn = (t & 1) ? xb0 : xb1;
        int i = (b << 8) + tid;
        xbn[i] = f2bf(x[((size_t)(t + 1) << 16) + i]);
      }
      v4f c00 = {0.f, 0.f, 0.f, 0.f};
      v4f c01 = c00, c10 = c00, c11 = c00, c20 = c00, c21 = c00;
      #pragma unroll
      for (int kk = 0; kk < 8; ++kk) {
        v8s q0 = *(const v8s*)(apB + kk * 32);
        v8s q1 = *(const v8s*)(apB + kk * 32 + 256);   // K-chunk kk+8
        unsigned oa = (((unsigned)(kk << 6)) | ((unsigned)(quad << 4))) ^ swz;
        unsigned ob = (((unsigned)((kk + 8) << 6)) | ((unsigned)(quad << 4))) ^ swz;
        v8s w0a = *(const v8s*)(w2s + (l15)      * 1024 + oa);
        v8s w1a = *(const v8s*)(w2s + (16 + l15) * 1024 + oa);
        v8s w2a = *(const v8s*)(w2s + (32 + l15) * 1024 + oa);
        v8s w0b = *(const v8s*)(w2s + (l15)      * 1024 + ob);
        v8s w1b = *(const v8s*)(w2s + (16 + l15) * 1024 + ob);
        v8s w2b = *(const v8s*)(w2s + (32 + l15) * 1024 + ob);
        c00 = __builtin_amdgcn_mfma_f32_16x16x32_bf16(q0, w0a, c00, 0, 0, 0);
        c10 = __builtin_amdgcn_mfma_f32_16x16x32_bf16(q0, w1a, c10, 0, 0, 0);
        c20 = __builtin_amdgcn_mfma_f32_16x16x32_bf16(q0, w2a, c20, 0, 0, 0);
        c01 = __builtin_amdgcn_mfma_f32_16x16x32_bf16(q1, w0b, c01, 0, 0, 0);
        c11 = __builtin_amdgcn_mfma_f32_16x16x32_bf16(q1, w1b, c11, 0, 0, 0);
        c21 = __builtin_amdgcn_mfma_f32_16x16x32_bf16(q1, w2b, c21, 0, 0, 0);
      }
      v4f r0 = c00 + c01, r1 = c10 + c11, r2 = c20 + c21;
      {
        float* eb = ew + ((w << 4) + (quad << 2)) * 49 + l15;  // [64m][49]
        #pragma unroll
        for (int r = 0; r < 4; ++r) {
          eb[r * 49]      = r0[r];
          eb[r * 49 + 16] = r1[r];
          eb[r * 49 + 32] = r2[r];
        }
      }
      __syncthreads();
      {
        int p = tid << 1;
        int m = p >> 3, jj = p & 7;        // jj even
        const float* e = ew + m * 49;      // cols: h3 0-7 | r 8-15 | z 16-23 | inn 24-31 | hn 32-39
        float h3a = e[jj]     + b2s[jj];
        float h3b = e[jj + 1] + b2s[jj + 1];
        float ra = sigf(e[8 + jj]   + b2s[8 + jj]);
        float rb = sigf(e[9 + jj]   + b2s[9 + jj]);
        float za = sigf(e[16 + jj]  + b2s[16 + jj]);
        float zb = sigf(e[17 + jj]  + b2s[17 + jj]);
        float na = tanhf(e[24 + jj] + b2s[24 + jj] + ra * (e[32 + jj] + b2s[32 + jj]));
        float nb = tanhf(e[25 + jj] + b2s[25 + jj] + rb * (e[33 + jj] + b2s[33 + jj]));
        float ha = (1.f - za) * na + za * h3a;
        float hb = (1.f - zb) * nb + zb * h3b;
        size_t o = ((size_t)(m0B + m) << 9) + (jbB << 3) + jj;
        *(unsigned*)(hx + o) = (unsigned)f2bf(ha) | ((unsigned)f2bf(hb) << 16);
        float* op = out + ((size_t)t << 17) + o;
        __builtin_nontemporal_store(ha, op);
        __builtin_nontemporal_store(hb, op + 1);
        if (t == T_ - 1) {                 // hx tail = outputs[511]
          out[67108864 + o]     = ha;
          out[67108864 + o + 1] = hb;
        }
      }
    }
    gridbar(bar, grpsel, (unsigned)(2 * t + 3));
  }
  // cx tail (block-local LDS -> out; no barrier needed)
  {
    int p = tid << 1;
    int m = p >> 4, j = p & 15;
    float2 cv; cv.x = cxs[p]; cv.y = cxs[p + 1];
    *(float2*)(out + 67239936 + ((size_t)(m0A + m) << 9) + j0A + j) = cv;
  }
}

// ---------------- launcher ----------------

extern "C" void kernel_launch(void* const* d_in, const int* in_sizes, int n_in,
                              void* d_out, int out_size, void* d_ws, size_t ws_size,
                              hipStream_t stream)
{
  const float* x     = (const float*)d_in[0];
  const float* Wih   = (const float*)d_in[1];
  const float* Whh   = (const float*)d_in[2];
  const float* bih   = (const float*)d_in[3];
  const float* bhh   = (const float*)d_in[4];
  const float* phase = (const float*)d_in[5];
  const float* feW   = (const float*)d_in[6];
  const float* feb   = (const float*)d_in[7];
  const float* gWih  = (const float*)d_in[8];
  const float* gWhh  = (const float*)d_in[9];
  const float* gbih  = (const float*)d_in[10];
  const float* gbhh  = (const float*)d_in[11];

  char* p = (char*)d_ws;
  unsigned short* W1 = (unsigned short*)p; p += (size_t)2048 * 768 * 2;  // 3 MB
  unsigned short* W2 = (unsigned short*)p; p += (size_t)2560 * 512 * 2;  // 2.5 MB
  float* b1    = (float*)p; p += 8192;
  float* bias2 = (float*)p; p += 10240;
  float* M1f   = (float*)p; p += (size_t)512 * 512 * 4;                  // 1 MB
  unsigned short* hx  = (unsigned short*)p; p += 262144;
  unsigned short* h1  = (unsigned short*)p; p += 262144;
  unsigned short* xb0 = (unsigned short*)p; p += 131072;
  unsigned short* xb1 = (unsigned short*)p; p += 131072;
  unsigned* bar = (unsigned*)p; p += 8192;

  k_setup_w1<<<6144, 256, 0, stream>>>(Wih, Whh, bih, bhh, W1, b1);
  k_m1<<<1024, 256, 0, stream>>>(phase, feW, M1f);
  k_setup_w2<<<5120, 256, 0, stream>>>(M1f, gWih, gWhh, W2);
  k_setup_bias2<<<10, 256, 0, stream>>>(feb, gWih, gWhh, gbih, gbhh, bias2);
  k_init<<<256, 256, 0, stream>>>(hx, bar);

  float* out = (float*)d_out;
  {
    const float* a0 = x;
    const unsigned short* a1 = W1;
    const float* a2 = b1;
    const unsigned short* a3 = W2;
    const float* a4 = bias2;
    unsigned short* a5 = hx;
    unsigned short* a6 = h1;
    unsigned short* a7 = xb0;
    unsigned short* a8 = xb1;
    float* a9 = out;
    unsigned* a10 = bar;
    void* args[11] = {&a0, &a1, &a2, &a3, &a4, &a5, &a6, &a7, &a8, &a9, &a10};
    hipLaunchCooperativeKernel(k_persist, dim3(256), dim3(256), args, 0u, stream);
  }
}